// Round 1
// baseline (71.355 us; speedup 1.0000x reference)
//
#include <hip/hip_runtime.h>
#include <hip/hip_bf16.h>

#define NEGINF -1000000000.0f

typedef __attribute__((ext_vector_type(4))) float f32x4;
typedef __attribute__((ext_vector_type(8))) short bf16x8;
typedef __attribute__((ext_vector_type(4))) short short4v;

constexpr int Bn = 64, Cn = 1024, Qn = 128, Dn = 128, CT = 128;

__device__ inline short f2bf(float x) {
    return (short)__builtin_bit_cast(unsigned short, __float2bfloat16(x));
}
__device__ inline float bf2f(short h) {
    unsigned u = ((unsigned)(unsigned short)h) << 16;
    return __builtin_bit_cast(float, u);
}

// K1: per (b, ctile of 128): S^T via MFMA (hi/lo split), softmax over q,
// c2q via MFMA, writes out cols [128:256) and [256:384), stores m[b,c] to ws.
__global__ __launch_bounds__(256) void k1_kernel(
    const float* __restrict__ ctx, const float* __restrict__ qry,
    const float* __restrict__ W, const float* __restrict__ mask,
    float* __restrict__ out, float* __restrict__ ws_m)
{
    __shared__ short qT[128][136];   // query^T bf16, padded rows (272B)
    __shared__ float qt_s[128];      // q_term + mask offset
    __shared__ float ct_s[128];      // c_term for this ctile
    __shared__ float w_lds[384];

    const int b = blockIdx.y, c0 = blockIdx.x * CT;
    const int tid = threadIdx.x;
    const float* ctxB = ctx + (size_t)b * Cn * Dn;
    const float* qryB = qry + (size_t)b * Qn * Dn;

    for (int i = tid; i < 384; i += 256) w_lds[i] = W[i];
    __syncthreads();

    // Pass A: stage qT (bf16) + compute qt_s = q_term + (1-mask)*NEGINF
    {
        int q = tid >> 1, h = tid & 1;
        const float* qrow = qryB + q * Dn + h * 64;
        float acc = 0.f;
        for (int j = 0; j < 64; j += 4) {
            f32x4 v = *(const f32x4*)(qrow + j);
            int d = h * 64 + j;
            acc += v.x * w_lds[128 + d] + v.y * w_lds[128 + d + 1]
                 + v.z * w_lds[128 + d + 2] + v.w * w_lds[128 + d + 3];
            qT[d + 0][q] = f2bf(v.x);
            qT[d + 1][q] = f2bf(v.y);
            qT[d + 2][q] = f2bf(v.z);
            qT[d + 3][q] = f2bf(v.w);
        }
        acc += __shfl_xor(acc, 1);
        if (h == 0) qt_s[q] = acc + (1.0f - mask[b * Qn + q]) * NEGINF;
    }
    // Pass B: c_term for this ctile
    {
        int c = tid >> 1, h = tid & 1;
        const float* crow = ctxB + (size_t)(c0 + c) * Dn + h * 64;
        float acc = 0.f;
        for (int j = 0; j < 64; j += 4) {
            f32x4 v = *(const f32x4*)(crow + j);
            int d = h * 64 + j;
            acc += v.x * w_lds[d] + v.y * w_lds[d + 1]
                 + v.z * w_lds[d + 2] + v.w * w_lds[d + 3];
        }
        acc += __shfl_xor(acc, 1);
        if (h == 0) ct_s[c] = acc;
    }
    __syncthreads();

    const int wave = tid >> 6, lane = tid & 63;
    const int g = lane >> 4, l15 = lane & 15;
    const int cw = wave * 32;  // this wave's c-local base (32 columns)

    // ---------- matmul 1: S^T[q][c] = sum_d query[q][d] * (ctx[c][d]*w_s[d])
    // A = query rows (M=q, 8 Mtiles), B = a-ctx cols (N=c, 2 Ntiles/wave), K=d (4 steps)
    f32x4 acc1[8][2] = {};

    for (int kk = 0; kk < 4; ++kk) {
        const int dbase = kk * 32 + g * 8;
        float wsv[8];
#pragma unroll
        for (int j = 0; j < 8; ++j) wsv[j] = w_lds[256 + dbase + j];

        bf16x8 qhi[8], qlo[8];
#pragma unroll
        for (int mt = 0; mt < 8; ++mt) {
            const float* p = qryB + (mt * 16 + l15) * Dn + dbase;
            f32x4 v0 = *(const f32x4*)p;
            f32x4 v1 = *(const f32x4*)(p + 4);
            float vv[8] = {v0.x, v0.y, v0.z, v0.w, v1.x, v1.y, v1.z, v1.w};
#pragma unroll
            for (int j = 0; j < 8; ++j) {
                short h = f2bf(vv[j]);
                qhi[mt][j] = h;
                qlo[mt][j] = f2bf(vv[j] - bf2f(h));
            }
        }
        bf16x8 ahi[2], alo[2];
#pragma unroll
        for (int nt = 0; nt < 2; ++nt) {
            const float* p = ctxB + (size_t)(c0 + cw + nt * 16 + l15) * Dn + dbase;
            f32x4 v0 = *(const f32x4*)p;
            f32x4 v1 = *(const f32x4*)(p + 4);
            float vv[8] = {v0.x, v0.y, v0.z, v0.w, v1.x, v1.y, v1.z, v1.w};
#pragma unroll
            for (int j = 0; j < 8; ++j) {
                float a = vv[j] * wsv[j];
                short h = f2bf(a);
                ahi[nt][j] = h;
                alo[nt][j] = f2bf(a - bf2f(h));
            }
        }
#pragma unroll
        for (int mt = 0; mt < 8; ++mt)
#pragma unroll
            for (int nt = 0; nt < 2; ++nt) {
                acc1[mt][nt] = __builtin_amdgcn_mfma_f32_16x16x32_bf16(qhi[mt], ahi[nt], acc1[mt][nt], 0, 0, 0);
                acc1[mt][nt] = __builtin_amdgcn_mfma_f32_16x16x32_bf16(qhi[mt], alo[nt], acc1[mt][nt], 0, 0, 0);
                acc1[mt][nt] = __builtin_amdgcn_mfma_f32_16x16x32_bf16(qlo[mt], ahi[nt], acc1[mt][nt], 0, 0, 0);
            }
    }

    // D-layout of acc1: row q = mt*16 + g*4 + r, col c = cw + nt*16 + l15.
    // Add qt' (q_term + mask). c_term is per-c: cancels in softmax over q.
#pragma unroll
    for (int mt = 0; mt < 8; ++mt)
#pragma unroll
        for (int r = 0; r < 4; ++r) {
            float qv = qt_s[mt * 16 + g * 4 + r];
            acc1[mt][0][r] += qv;
            acc1[mt][1][r] += qv;
        }

    // softmax over q per column c; record m[c] = colmax + c_term[c]
    float psum[2];
#pragma unroll
    for (int nt = 0; nt < 2; ++nt) {
        float mx = -3.4e38f;
#pragma unroll
        for (int mt = 0; mt < 8; ++mt)
#pragma unroll
            for (int r = 0; r < 4; ++r) mx = fmaxf(mx, acc1[mt][nt][r]);
        mx = fmaxf(mx, __shfl_xor(mx, 16));
        mx = fmaxf(mx, __shfl_xor(mx, 32));
        float sum = 0.f;
#pragma unroll
        for (int mt = 0; mt < 8; ++mt)
#pragma unroll
            for (int r = 0; r < 4; ++r) {
                float p = __expf(acc1[mt][nt][r] - mx);
                acc1[mt][nt][r] = p;
                sum += p;
            }
        sum += __shfl_xor(sum, 16);
        sum += __shfl_xor(sum, 32);
        psum[nt] = sum;
        int cl = cw + nt * 16 + l15;
        if (g == 0) ws_m[(size_t)b * Cn + c0 + cl] = mx + ct_s[cl];
    }

    // Pack P^T into A-fragments for matmul2 using k-bijection k = g*4+(j&3)+16*(j>>2)
    bf16x8 pa[4][2];
#pragma unroll
    for (int kk2 = 0; kk2 < 4; ++kk2)
#pragma unroll
        for (int nt = 0; nt < 2; ++nt) {
            bf16x8 f;
#pragma unroll
            for (int j = 0; j < 8; ++j) {
                f[j] = f2bf(acc1[2 * kk2 + (j >> 2)][nt][j & 3]);
            }
            pa[kk2][nt] = f;
        }

    // 1/colsum for the rows this lane will hold in acc2 (c = cw + nt1*16 + g*4 + r)
    float inv[2][4];
#pragma unroll
    for (int nt1 = 0; nt1 < 2; ++nt1)
#pragma unroll
        for (int r = 0; r < 4; ++r)
            inv[nt1][r] = 1.0f / __shfl(psum[nt1], g * 4 + r);

    // ---------- matmul 2: c2q[c][d] = sum_q P[c][q] * query[q][d]
    f32x4 acc2[2][8] = {};
#pragma unroll
    for (int kk2 = 0; kk2 < 4; ++kk2) {
        bf16x8 qb[8];
#pragma unroll
        for (int ntD = 0; ntD < 8; ++ntD) {
            const short* base = &qT[ntD * 16 + l15][kk2 * 32 + g * 4];
            short4v r0 = *(const short4v*)(base);
            short4v r1 = *(const short4v*)(base + 16);
            bf16x8 f;
            f[0] = r0[0]; f[1] = r0[1]; f[2] = r0[2]; f[3] = r0[3];
            f[4] = r1[0]; f[5] = r1[1]; f[6] = r1[2]; f[7] = r1[3];
            qb[ntD] = f;
        }
#pragma unroll
        for (int nt1 = 0; nt1 < 2; ++nt1)
#pragma unroll
            for (int ntD = 0; ntD < 8; ++ntD)
                acc2[nt1][ntD] = __builtin_amdgcn_mfma_f32_16x16x32_bf16(pa[kk2][nt1], qb[ntD], acc2[nt1][ntD], 0, 0, 0);
    }

    // epilogue: write cols 1 (c2q) and 2 (ctx*c2q)
#pragma unroll
    for (int nt1 = 0; nt1 < 2; ++nt1)
#pragma unroll
        for (int r = 0; r < 4; ++r) {
            int cl = cw + nt1 * 16 + g * 4 + r;
            const float* crow = ctxB + (size_t)(c0 + cl) * Dn;
            float* orow = out + ((size_t)b * Cn + c0 + cl) * 512;
            float is = inv[nt1][r];
#pragma unroll
            for (int ntD = 0; ntD < 8; ++ntD) {
                int d = ntD * 16 + l15;
                float c2q = acc2[nt1][ntD][r] * is;
                float cv = crow[d];
                orow[128 + d] = c2q;
                orow[256 + d] = cv * c2q;
            }
        }
}

// K2: per (b, cgroup of 128): softmax over c of m, partial q2c -> ws_part
__global__ __launch_bounds__(256) void k2_kernel(
    const float* __restrict__ ctx, const float* __restrict__ ws_m,
    float* __restrict__ ws_part)
{
    __shared__ float red[256];
    __shared__ float wv[128];
    const int cg = blockIdx.x, b = blockIdx.y;
    const int t = threadIdx.x;
    const float* mrow = ws_m + (size_t)b * Cn;

    f32x4 v = *(const f32x4*)(mrow + t * 4);
    float mx = fmaxf(fmaxf(v.x, v.y), fmaxf(v.z, v.w));
    red[t] = mx;
    __syncthreads();
    for (int s = 128; s > 0; s >>= 1) {
        if (t < s) red[t] = fmaxf(red[t], red[t + s]);
        __syncthreads();
    }
    float M = red[0];
    __syncthreads();
    float sm = __expf(v.x - M) + __expf(v.y - M) + __expf(v.z - M) + __expf(v.w - M);
    red[t] = sm;
    __syncthreads();
    for (int s = 128; s > 0; s >>= 1) {
        if (t < s) red[t] += red[t + s];
        __syncthreads();
    }
    float invL = 1.0f / red[0];
    __syncthreads();

    if (t < 128) wv[t] = __expf(mrow[cg * 128 + t] - M) * invL;
    __syncthreads();

    const int d = t & 127, rh = t >> 7;
    const float* cb = ctx + ((size_t)b * Cn + cg * 128 + rh * 64) * Dn;
    float acc = 0.f;
    for (int i = 0; i < 64; ++i)
        acc += wv[rh * 64 + i] * cb[(size_t)i * Dn + d];

    red[t] = acc;
    __syncthreads();
    if (t < 128)
        ws_part[((size_t)b * 8 + cg) * 128 + t] = red[t] + red[t + 128];
}

// K3: reduce partials -> q2c; write cols 0 (ctx) and 3 (ctx*q2c)
__global__ __launch_bounds__(256) void k3_kernel(
    const float* __restrict__ ctx, const float* __restrict__ ws_part,
    float* __restrict__ out)
{
    __shared__ float q2c[128];
    const int ct = blockIdx.x, b = blockIdx.y;
    const int t = threadIdx.x;
    if (t < 128) {
        float s = 0.f;
        for (int cg = 0; cg < 8; ++cg)
            s += ws_part[((size_t)b * 8 + cg) * 128 + t];
        q2c[t] = s;
    }
    __syncthreads();
    const float* cb = ctx + ((size_t)b * Cn + ct * CT) * Dn;
    float* ob = out + ((size_t)b * Cn + ct * CT) * 512;
    for (int i4 = t; i4 < 128 * 32; i4 += 256) {
        int c = i4 >> 5, d4 = (i4 & 31) * 4;
        f32x4 v = *(const f32x4*)(cb + c * 128 + d4);
        f32x4 q = *(const f32x4*)(&q2c[d4]);
        *(f32x4*)(ob + (size_t)c * 512 + d4) = v;
        f32x4 w;
        w.x = v.x * q.x; w.y = v.y * q.y; w.z = v.z * q.z; w.w = v.w * q.w;
        *(f32x4*)(ob + (size_t)c * 512 + 384 + d4) = w;
    }
}

extern "C" void kernel_launch(void* const* d_in, const int* in_sizes, int n_in,
                              void* d_out, int out_size, void* d_ws, size_t ws_size,
                              hipStream_t stream) {
    const float* ctx  = (const float*)d_in[0];
    const float* qry  = (const float*)d_in[1];
    const float* W    = (const float*)d_in[2];
    const float* mask = (const float*)d_in[3];
    float* out = (float*)d_out;
    float* ws_m    = (float*)d_ws;            // 64*1024 f32 = 256 KB
    float* ws_part = ws_m + (size_t)Bn * Cn;  // 64*8*128 f32 = 256 KB

    k1_kernel<<<dim3(Cn / CT, Bn), 256, 0, stream>>>(ctx, qry, W, mask, out, ws_m);
    k2_kernel<<<dim3(8, Bn), 256, 0, stream>>>(ctx, ws_m, ws_part);
    k3_kernel<<<dim3(Cn / CT, Bn), 256, 0, stream>>>(ctx, ws_part, out);
}